// Round 1
// baseline (1918.571 us; speedup 1.0000x reference)
//
#include <hip/hip_runtime.h>

constexpr int Hh = 160, Ww = 160, Bb = 8, Cc = 256, ICn = 32;
constexpr int HWn = Hh * Ww;                 // 25600
constexpr float EPSf = 1e-5f;

// ws float offsets
constexpr int P_QKVW = 0;        // [256][96]
constexpr int P_QKVB = 24576;    // [96]
constexpr int P_QKVA = 24672;    // [96]
constexpr int P_DW   = 24768;    // [3][32][3][3][32]
constexpr int P_DB   = 52416;    // [3][32]
constexpr int P_OW   = 52512;    // [256][96]
constexpr int P_OB   = 77088;    // [256]
constexpr int P_OA   = 77344;    // [1]
constexpr int PLANE  = Bb * ICn * HWn;       // 6,553,600
constexpr int OFF_Q  = 77824;
constexpr int OFF_K  = OFF_Q + PLANE;
constexpr int OFF_V  = OFF_Q + 2 * PLANE;
constexpr int OFF_T  = OFF_Q + 3 * PLANE;    // t0,t1,t2
constexpr int OFF_CAT= OFF_Q + 6 * PLANE;    // 3*PLANE floats

struct InPtrs { const float* p[40]; };

// ---------------- prep: fold BN into weights/biases ----------------
__global__ void k_prep(InPtrs in, float* __restrict__ ws) {
    int idx = blockIdx.x * 256 + threadIdx.x;
    if (idx < 24576) {
        int c = idx / 96, oc = idx % 96;
        int z = oc >> 5, o = oc & 31;
        const float* wz = in.p[1 + 6 * z];
        float s = in.p[2 + 6 * z][o] * rsqrtf(in.p[5 + 6 * z][o] + EPSf);
        ws[P_QKVW + idx] = wz[o * 256 + c] * s;
    } else if (idx < 24672) {
        int oc = idx - 24576; int z = oc >> 5, o = oc & 31;
        float s = in.p[2 + 6 * z][o] * rsqrtf(in.p[5 + 6 * z][o] + EPSf);
        ws[P_QKVB + oc] = in.p[3 + 6 * z][o] - in.p[4 + 6 * z][o] * s;
    } else if (idx < 24768) {
        int oc = idx - 24672; int z = oc >> 5;
        ws[P_QKVA + oc] = in.p[6 + 6 * z][0];
    } else if (idx < 52416) {
        int j = idx - 24768;
        int d = j / 9216, r2 = j % 9216;
        int oc = r2 & 31; int tmp = r2 >> 5;
        int kx = tmp % 3; tmp /= 3; int ky = tmp % 3; int ic2 = tmp / 3;
        const float* wd = in.p[19 + 5 * d];
        float s = in.p[20 + 5 * d][oc] * rsqrtf(in.p[23 + 5 * d][oc] + EPSf);
        ws[P_DW + j] = wd[((oc * 32 + ic2) * 3 + ky) * 3 + kx] * s;
    } else if (idx < 52512) {
        int j = idx - 52416; int d = j >> 5, oc = j & 31;
        float s = in.p[20 + 5 * d][oc] * rsqrtf(in.p[23 + 5 * d][oc] + EPSf);
        ws[P_DB + j] = in.p[21 + 5 * d][oc] - in.p[22 + 5 * d][oc] * s;
    } else if (idx < 77088) {
        int j = idx - 52512; int c = j / 96;
        float s = in.p[35][c] * rsqrtf(in.p[38][c] + EPSf);
        ws[P_OW + j] = in.p[34][j] * s;
    } else if (idx < 77344) {
        int c = idx - 77088;
        float s = in.p[35][c] * rsqrtf(in.p[38][c] + EPSf);
        ws[P_OB + c] = in.p[36][c] - in.p[37][c] * s;
    } else if (idx == 77344) {
        ws[P_OA] = in.p[39][0];
    }
}

// ---------------- fused q/k/v 1x1 conv + BN + PReLU ----------------
// grid 3200, block 256 = 4 oc-groups x 64 positions; LDS-staged feature tile.
__global__ __launch_bounds__(256) void k_qkv(const float* __restrict__ feat,
                                             float* __restrict__ ws) {
    __shared__ float fts[64 * 64];
    const int tid = threadIdx.x;
    const int pos = tid & 63;
    const int ocg = tid >> 6;            // 0..3, wave-uniform
    const int n0 = blockIdx.x * 64;
    const int b = n0 / HWn;
    const int hw0 = n0 % HWn;
    const float* fbase = feat + (long)b * Cc * HWn + hw0;
    const float* __restrict__ wq = ws + P_QKVW;
    float acc[24];
#pragma unroll
    for (int a = 0; a < 24; a++) acc[a] = 0.f;
    const int oc0 = ocg * 24;
    for (int cc = 0; cc < 4; cc++) {
        __syncthreads();
#pragma unroll
        for (int l = 0; l < 16; l++) {
            int li = tid + l * 256;
            int cl = li >> 6, pp = li & 63;
            fts[li] = fbase[(cc * 64 + cl) * HWn + pp];
        }
        __syncthreads();
#pragma unroll 4
        for (int cl = 0; cl < 64; cl++) {
            float f = fts[cl * 64 + pos];
            const float* wrow = wq + (cc * 64 + cl) * 96 + oc0;
#pragma unroll
            for (int a = 0; a < 24; a++) acc[a] += f * wrow[a];
        }
    }
#pragma unroll
    for (int a = 0; a < 24; a++) {
        int oc = oc0 + a;
        float y = acc[a] + ws[P_QKVB + oc];
        float al = ws[P_QKVA + oc];
        y = y >= 0.f ? y : al * y;
        int z = oc >> 5, o = oc & 31;
        ws[OFF_Q + z * PLANE + (b * ICn + o) * HWn + hw0 + pos] = y;
    }
}

// ---------------- dilated 3x3 convs + BN + ReLU ----------------
// grid (800, 3), block 256: one thread per pixel computes all 32 oc.
__global__ __launch_bounds__(256) void k_dconv(float* __restrict__ ws) {
    const int d = blockIdx.y;
    const int dil = 1 + 2 * d;
    const int n = blockIdx.x * 256 + threadIdx.x;
    const int b = n / HWn, hw = n % HWn;
    const int h = hw / Ww, w = hw % Ww;
    const float* __restrict__ vbase = ws + OFF_V + b * ICn * HWn;
    const float* __restrict__ wd = ws + P_DW + d * 9216;
    const float* __restrict__ bd = ws + P_DB + d * 32;
    float acc[32];
#pragma unroll
    for (int o = 0; o < 32; o++) acc[o] = 0.f;
    for (int ic = 0; ic < ICn; ic++) {
        const float* vp = vbase + ic * HWn;
        float v[9];
#pragma unroll
        for (int ky = 0; ky < 3; ky++) {
            int hh = h + dil * (ky - 1);
            bool hok = (unsigned)hh < 160u;
#pragma unroll
            for (int kx = 0; kx < 3; kx++) {
                int wwp = w + dil * (kx - 1);
                bool ok = hok && ((unsigned)wwp < 160u);
                v[ky * 3 + kx] = ok ? vp[hh * Ww + wwp] : 0.f;
            }
        }
        const float* wr = wd + ic * 288;
#pragma unroll
        for (int k = 0; k < 9; k++) {
            float vv = v[k];
            const float* wk = wr + k * 32;
#pragma unroll
            for (int o = 0; o < 32; o++) acc[o] += vv * wk[o];
        }
    }
    float* tout = ws + OFF_T + d * PLANE + b * ICn * HWn + hw;
#pragma unroll
    for (int o = 0; o < 32; o++) {
        float y = acc[o] + bd[o];
        tout[o * HWn] = fmaxf(y, 0.f);
    }
}

// ---------------- attention + softmax + 3x PV (fused) ----------------
// one block per (b,w); att[160][160] f32 in LDS; XCD-swizzled block mapping.
__global__ __launch_bounds__(320) void k_att(float* __restrict__ ws) {
    extern __shared__ float lds[];
    float* att = lds;                 // 25600
    float* qs  = lds + 25600;         // 5120
    float* ks  = lds + 30720;         // 5120
    const int tid = threadIdx.x;
    const int bid = blockIdx.x;
    // swizzle: XCD r owns w in [20r, 20r+20) for all b -> L2 line reuse (16 w per 64B line)
    const int r = bid & 7, qq = bid >> 3;
    const int b = qq / 20;
    const int w = r * 20 + (qq % 20);
    const int bw = b * Ww + w;
    const float* qg = ws + OFF_Q + b * ICn * HWn + w;
    const float* kg = ws + OFF_K + b * ICn * HWn + w;
    for (int l = tid; l < 5120; l += 320) {
        int ic = l / 160, hh = l % 160;
        qs[l] = qg[ic * HWn + hh * Ww];
        ks[l] = kg[ic * HWn + hh * Ww];
    }
    __syncthreads();
    // att = q^T k, 4x4 register tiles (40x40 tiles, 5 per thread)
    for (int p = 0; p < 5; p++) {
        int tt = tid + p * 320;
        int h1 = (tt / 40) * 4, h2 = (tt % 40) * 4;
        float acc[4][4];
#pragma unroll
        for (int x = 0; x < 4; x++)
#pragma unroll
            for (int y = 0; y < 4; y++) acc[x][y] = 0.f;
        for (int ic = 0; ic < 32; ic++) {
            float4 qv = *(const float4*)(qs + ic * 160 + h1);
            float4 kv = *(const float4*)(ks + ic * 160 + h2);
            float qa[4] = {qv.x, qv.y, qv.z, qv.w};
            float kb[4] = {kv.x, kv.y, kv.z, kv.w};
#pragma unroll
            for (int x = 0; x < 4; x++)
#pragma unroll
                for (int y = 0; y < 4; y++) acc[x][y] += qa[x] * kb[y];
        }
#pragma unroll
        for (int x = 0; x < 4; x++)
            *(float4*)(att + (h1 + x) * 160 + h2) =
                make_float4(acc[x][0], acc[x][1], acc[x][2], acc[x][3]);
    }
    __syncthreads();
    // softmax over rows: 5 waves x 32 rows
    const int wave = tid >> 6, lane = tid & 63;
    for (int rr = 0; rr < 32; rr++) {
        int row = wave * 32 + rr;
        float* ar = att + row * 160;
        float x0 = ar[lane];
        float x1 = ar[lane + 64];
        float x2 = (lane < 32) ? ar[lane + 128] : -3.4e38f;
        float m = fmaxf(fmaxf(x0, x1), x2);
#pragma unroll
        for (int off = 32; off > 0; off >>= 1) m = fmaxf(m, __shfl_xor(m, off));
        float e0 = __expf(x0 - m);
        float e1 = __expf(x1 - m);
        float e2 = (lane < 32) ? __expf(x2 - m) : 0.f;
        float s = e0 + e1 + e2;
#pragma unroll
        for (int off = 32; off > 0; off >>= 1) s += __shfl_xor(s, off);
        float inv = 1.f / s;
        ar[lane] = e0 * inv;
        ar[lane + 64] = e1 * inv;
        if (lane < 32) ar[lane + 128] = e2 * inv;
    }
    // PV per branch; t slice staged in qs region (faithful raw-view == flat [IC][H])
    float* ts = qs;
    for (int d = 0; d < 3; d++) {
        __syncthreads();
        const float* tg = ws + OFF_T + d * PLANE + b * ICn * HWn + w;
        for (int l = tid; l < 5120; l += 320) {
            int ic = l / 160, hh = l % 160;
            ts[l] = tg[ic * HWn + hh * Ww];
        }
        __syncthreads();
        int h0 = (tid >> 3) * 4;
        int j0 = (tid & 7) * 4;
        float acc[4][4];
#pragma unroll
        for (int x = 0; x < 4; x++)
#pragma unroll
            for (int y = 0; y < 4; y++) acc[x][y] = 0.f;
#pragma unroll 2
        for (int i = 0; i < 160; i++) {
            float4 tv = *(const float4*)(ts + i * 32 + j0);
            float ta[4] = {tv.x, tv.y, tv.z, tv.w};
#pragma unroll
            for (int x = 0; x < 4; x++) {
                float av = att[(h0 + x) * 160 + i];
#pragma unroll
                for (int y = 0; y < 4; y++) acc[x][y] += av * ta[y];
            }
        }
        float* outp = ws + OFF_CAT + d * PLANE + bw * 5120;
#pragma unroll
        for (int x = 0; x < 4; x++)
            *(float4*)(outp + (h0 + x) * 32 + j0) =
                make_float4(acc[x][0], acc[x][1], acc[x][2], acc[x][3]);
    }
}

// ---------------- output 1x1 conv + BN + residual + PReLU ----------------
// grid 3200, block 256 = 4 ch-groups x 64 positions.
__global__ __launch_bounds__(256) void k_out(const float* __restrict__ feat,
                                             const float* __restrict__ ws,
                                             float* __restrict__ out) {
    __shared__ float rs[64 * 97];
    const int tid = threadIdx.x;
    const int n0 = blockIdx.x * 64;
    const int b = n0 / HWn;
    const int hw0 = n0 % HWn;
    for (int l = tid; l < 6144; l += 256) {
        int pos = l / 96, j = l % 96;
        int hw = hw0 + pos;
        int h = hw / Ww, w2 = hw % Ww;
        rs[pos * 97 + j] = ws[OFF_CAT + ((b * Ww + w2) * Hh + h) * 96 + j];
    }
    __syncthreads();
    const int pos = tid & 63;
    const int cg = tid >> 6;             // wave-uniform
    const int hw = hw0 + pos;
    const float* __restrict__ wo = ws + P_OW;
    const float alpha = ws[P_OA];
    for (int cb = 0; cb < 8; cb++) {
        int cbase = cb * 32 + cg * 8;
        float acc[8];
#pragma unroll
        for (int i = 0; i < 8; i++) acc[i] = 0.f;
#pragma unroll 4
        for (int j = 0; j < 96; j++) {
            float rv = rs[pos * 97 + j];
#pragma unroll
            for (int i = 0; i < 8; i++) acc[i] += rv * wo[(cbase + i) * 96 + j];
        }
#pragma unroll
        for (int i = 0; i < 8; i++) {
            int c = cbase + i;
            long off = (long)(b * Cc + c) * HWn + hw;
            float y = acc[i] + ws[P_OB + c] + feat[off];
            out[off] = y >= 0.f ? y : alpha * y;
        }
    }
}

extern "C" void kernel_launch(void* const* d_in, const int* in_sizes, int n_in,
                              void* d_out, int out_size, void* d_ws, size_t ws_size,
                              hipStream_t stream) {
    InPtrs ip;
    for (int i = 0; i < 40; i++) ip.p[i] = (const float*)d_in[i];
    float* ws = (float*)d_ws;
    const float* feat = (const float*)d_in[0];
    float* out = (float*)d_out;

    k_prep<<<304, 256, 0, stream>>>(ip, ws);
    k_qkv<<<3200, 256, 0, stream>>>(feat, ws);
    k_dconv<<<dim3(800, 3, 1), 256, 0, stream>>>(ws);
    (void)hipFuncSetAttribute(reinterpret_cast<const void*>(k_att),
                              hipFuncAttributeMaxDynamicSharedMemorySize, 143360);
    k_att<<<1280, 320, 143360, stream>>>(ws);
    k_out<<<3200, 256, 0, stream>>>(feat, ws, out);
}

// Round 2
// 1092.514 us; speedup vs baseline: 1.7561x; 1.7561x over previous
//
#include <hip/hip_runtime.h>

constexpr int Hh = 160, Ww = 160, Bb = 8, Cc = 256, ICn = 32;
constexpr int HWn = Hh * Ww;                 // 25600
constexpr float EPSf = 1e-5f;

// ws float offsets
constexpr int P_QKVW = 0;        // [256][96]
constexpr int P_QKVB = 24576;    // [96]
constexpr int P_QKVA = 24672;    // [96]
constexpr int P_DW   = 24768;    // [3][32][3][3][32]
constexpr int P_DB   = 52416;    // [3][32]
constexpr int P_OW   = 52512;    // [256][96]
constexpr int P_OB   = 77088;    // [256]
constexpr int P_OA   = 77344;    // [1]
constexpr int PLANE  = Bb * ICn * HWn;       // 6,553,600
constexpr int OFF_Q  = 77824;
constexpr int OFF_K  = OFF_Q + PLANE;
constexpr int OFF_V  = OFF_Q + 2 * PLANE;
constexpr int OFF_T  = OFF_Q + 3 * PLANE;    // t0,t1,t2
constexpr int OFF_CAT= OFF_Q + 6 * PLANE;    // 3*PLANE floats

struct InPtrs { const float* p[40]; };

// ---------------- prep: fold BN into weights/biases ----------------
__global__ void k_prep(InPtrs in, float* __restrict__ ws) {
    int idx = blockIdx.x * 256 + threadIdx.x;
    if (idx < 24576) {
        int c = idx / 96, oc = idx % 96;
        int z = oc >> 5, o = oc & 31;
        const float* wz = in.p[1 + 6 * z];
        float s = in.p[2 + 6 * z][o] * rsqrtf(in.p[5 + 6 * z][o] + EPSf);
        ws[P_QKVW + idx] = wz[o * 256 + c] * s;
    } else if (idx < 24672) {
        int oc = idx - 24576; int z = oc >> 5, o = oc & 31;
        float s = in.p[2 + 6 * z][o] * rsqrtf(in.p[5 + 6 * z][o] + EPSf);
        ws[P_QKVB + oc] = in.p[3 + 6 * z][o] - in.p[4 + 6 * z][o] * s;
    } else if (idx < 24768) {
        int oc = idx - 24672; int z = oc >> 5;
        ws[P_QKVA + oc] = in.p[6 + 6 * z][0];
    } else if (idx < 52416) {
        int j = idx - 24768;
        int d = j / 9216, r2 = j % 9216;
        int oc = r2 & 31; int tmp = r2 >> 5;
        int kx = tmp % 3; tmp /= 3; int ky = tmp % 3; int ic2 = tmp / 3;
        const float* wd = in.p[19 + 5 * d];
        float s = in.p[20 + 5 * d][oc] * rsqrtf(in.p[23 + 5 * d][oc] + EPSf);
        ws[P_DW + j] = wd[((oc * 32 + ic2) * 3 + ky) * 3 + kx] * s;
    } else if (idx < 52512) {
        int j = idx - 52416; int d = j >> 5, oc = j & 31;
        float s = in.p[20 + 5 * d][oc] * rsqrtf(in.p[23 + 5 * d][oc] + EPSf);
        ws[P_DB + j] = in.p[21 + 5 * d][oc] - in.p[22 + 5 * d][oc] * s;
    } else if (idx < 77088) {
        int j = idx - 52512; int c = j / 96;
        float s = in.p[35][c] * rsqrtf(in.p[38][c] + EPSf);
        ws[P_OW + j] = in.p[34][j] * s;
    } else if (idx < 77344) {
        int c = idx - 77088;
        float s = in.p[35][c] * rsqrtf(in.p[38][c] + EPSf);
        ws[P_OB + c] = in.p[36][c] - in.p[37][c] * s;
    } else if (idx == 77344) {
        ws[P_OA] = in.p[39][0];
    }
}

// ---------------- fused q/k/v 1x1 conv: GEMM M=96, K=256, N=204800 ----------------
// block 256 = 16 mg (6 oc each) x 16 ng (4+4 pos); tiles: K-chunk 64, N-tile 128.
__global__ __launch_bounds__(256) void k_qkv(const float* __restrict__ feat,
                                             float* __restrict__ ws) {
    __shared__ float As[64 * 96];    // [k][oc]
    __shared__ float Bs[64 * 128];   // [k][pos]
    const int tid = threadIdx.x;
    const int mg = tid >> 4;         // 0..15 -> oc0 = 6*mg
    const int ng = tid & 15;         // pos offsets 4*ng and 64+4*ng
    const int n0 = blockIdx.x * 128;
    const int b = n0 / HWn;
    const int hw0 = n0 % HWn;
    const float* fbase = feat + (size_t)b * Cc * HWn + hw0;
    const float* __restrict__ wq = ws + P_QKVW;
    float acc[6][8];
#pragma unroll
    for (int i = 0; i < 6; i++)
#pragma unroll
        for (int j = 0; j < 8; j++) acc[i][j] = 0.f;

    for (int kc = 0; kc < 4; kc++) {
        __syncthreads();
#pragma unroll
        for (int i = 0; i < 32; i++) {          // Bs: 8192 floats
            int l = tid + i * 256;
            int c = l >> 7, p = l & 127;
            Bs[l] = fbase[(kc * 64 + c) * HWn + p];
        }
#pragma unroll
        for (int i = 0; i < 24; i++) {          // As: 6144 floats (already [c][oc])
            int l = tid + i * 256;
            As[l] = wq[kc * 64 * 96 + l];
        }
        __syncthreads();
#pragma unroll 4
        for (int k = 0; k < 64; k++) {
            float2 a01 = *(const float2*)(As + k * 96 + 6 * mg);
            float2 a23 = *(const float2*)(As + k * 96 + 6 * mg + 2);
            float2 a45 = *(const float2*)(As + k * 96 + 6 * mg + 4);
            float av[6] = {a01.x, a01.y, a23.x, a23.y, a45.x, a45.y};
            float4 b0 = *(const float4*)(Bs + k * 128 + 4 * ng);
            float4 b1 = *(const float4*)(Bs + k * 128 + 64 + 4 * ng);
            float bv[8] = {b0.x, b0.y, b0.z, b0.w, b1.x, b1.y, b1.z, b1.w};
#pragma unroll
            for (int i = 0; i < 6; i++)
#pragma unroll
                for (int j = 0; j < 8; j++) acc[i][j] += av[i] * bv[j];
        }
    }
    // epilogue: bias + PReLU + scatter to Q/K/V planes
#pragma unroll
    for (int i = 0; i < 6; i++) {
        int oc = 6 * mg + i;
        float bb = ws[P_QKVB + oc];
        float aa = ws[P_QKVA + oc];
        int z = oc >> 5, o = oc & 31;
        float* qb = ws + OFF_Q + (size_t)z * PLANE + ((size_t)b * ICn + o) * HWn + hw0;
#pragma unroll
        for (int f = 0; f < 2; f++) {
            float4 y;
            float t0 = acc[i][f * 4 + 0] + bb; y.x = t0 >= 0.f ? t0 : aa * t0;
            float t1 = acc[i][f * 4 + 1] + bb; y.y = t1 >= 0.f ? t1 : aa * t1;
            float t2 = acc[i][f * 4 + 2] + bb; y.z = t2 >= 0.f ? t2 : aa * t2;
            float t3 = acc[i][f * 4 + 3] + bb; y.w = t3 >= 0.f ? t3 : aa * t3;
            *(float4*)(qb + f * 64 + 4 * ng) = y;
        }
    }
}

// ---------------- dilated 3x3 convs: weights in LDS, 2 pixels/thread ----------------
__global__ __launch_bounds__(256) void k_dconv(float* __restrict__ ws) {
    __shared__ float wsm[9216];      // [ic][9][32]
    const int d = blockIdx.y;
    const int dil = 1 + 2 * d;
    const int tid = threadIdx.x;
#pragma unroll
    for (int i = 0; i < 36; i++) wsm[tid + i * 256] = ws[P_DW + d * 9216 + tid + i * 256];
    __syncthreads();

    const int pix0 = blockIdx.x * 512 + tid * 2;
    const int b = pix0 / HWn;
    const int hw = pix0 % HWn;
    const int h = hw / Ww, w = hw % Ww;   // w even, w+1 in same row
    const float* __restrict__ vbase = ws + OFF_V + (size_t)b * ICn * HWn;

    int hoff[3]; bool hv[3];
    int wo0[3]; bool wv0[3], wv1[3];
#pragma unroll
    for (int t = 0; t < 3; t++) {
        int hh = h + dil * (t - 1);
        hv[t] = (unsigned)hh < 160u; hoff[t] = hh * Ww;
        int wp = w + dil * (t - 1);
        wv0[t] = (unsigned)wp < 160u; wv1[t] = (unsigned)(wp + 1) < 160u; wo0[t] = wp;
    }

    float acc[32][2];
#pragma unroll
    for (int o = 0; o < 32; o++) { acc[o][0] = 0.f; acc[o][1] = 0.f; }

    for (int ic = 0; ic < ICn; ic++) {
        const float* vp = vbase + ic * HWn;
        float v0[9], v1[9];
#pragma unroll
        for (int ky = 0; ky < 3; ky++)
#pragma unroll
            for (int kx = 0; kx < 3; kx++) {
                int kk = ky * 3 + kx;
                v0[kk] = (hv[ky] && wv0[kx]) ? vp[hoff[ky] + wo0[kx]] : 0.f;
                v1[kk] = (hv[ky] && wv1[kx]) ? vp[hoff[ky] + wo0[kx] + 1] : 0.f;
            }
        const float* wr = wsm + ic * 288;
#pragma unroll
        for (int k = 0; k < 9; k++) {
            float a0 = v0[k], a1 = v1[k];
#pragma unroll
            for (int oq = 0; oq < 8; oq++) {
                float4 wv = *(const float4*)(wr + k * 32 + 4 * oq);
                acc[4 * oq + 0][0] += a0 * wv.x; acc[4 * oq + 0][1] += a1 * wv.x;
                acc[4 * oq + 1][0] += a0 * wv.y; acc[4 * oq + 1][1] += a1 * wv.y;
                acc[4 * oq + 2][0] += a0 * wv.z; acc[4 * oq + 2][1] += a1 * wv.z;
                acc[4 * oq + 3][0] += a0 * wv.w; acc[4 * oq + 3][1] += a1 * wv.w;
            }
        }
    }
    float* tout = ws + OFF_T + (size_t)d * PLANE + (size_t)b * ICn * HWn + hw;
    const float* bd = ws + P_DB + d * 32;
#pragma unroll
    for (int o = 0; o < 32; o++) {
        float2 y;
        y.x = fmaxf(acc[o][0] + bd[o], 0.f);
        y.y = fmaxf(acc[o][1] + bd[o], 0.f);
        *(float2*)(tout + o * HWn) = y;
    }
}

// ---------------- attention + softmax + 3x PV (fused) ----------------
__global__ __launch_bounds__(320) void k_att(float* __restrict__ ws) {
    extern __shared__ float lds[];
    float* att = lds;                 // 25600
    float* qs  = lds + 25600;         // 5120
    float* ks  = lds + 30720;         // 5120
    const int tid = threadIdx.x;
    const int bid = blockIdx.x;
    const int r = bid & 7, qq = bid >> 3;
    const int b = qq / 20;
    const int w = r * 20 + (qq % 20);
    const int bw = b * Ww + w;
    const float* qg = ws + OFF_Q + b * ICn * HWn + w;
    const float* kg = ws + OFF_K + b * ICn * HWn + w;
    for (int l = tid; l < 5120; l += 320) {
        int ic = l / 160, hh = l % 160;
        qs[l] = qg[ic * HWn + hh * Ww];
        ks[l] = kg[ic * HWn + hh * Ww];
    }
    __syncthreads();
    for (int p = 0; p < 5; p++) {
        int tt = tid + p * 320;
        int h1 = (tt / 40) * 4, h2 = (tt % 40) * 4;
        float acc[4][4];
#pragma unroll
        for (int x = 0; x < 4; x++)
#pragma unroll
            for (int y = 0; y < 4; y++) acc[x][y] = 0.f;
        for (int ic = 0; ic < 32; ic++) {
            float4 qv = *(const float4*)(qs + ic * 160 + h1);
            float4 kv = *(const float4*)(ks + ic * 160 + h2);
            float qa[4] = {qv.x, qv.y, qv.z, qv.w};
            float kb[4] = {kv.x, kv.y, kv.z, kv.w};
#pragma unroll
            for (int x = 0; x < 4; x++)
#pragma unroll
                for (int y = 0; y < 4; y++) acc[x][y] += qa[x] * kb[y];
        }
#pragma unroll
        for (int x = 0; x < 4; x++)
            *(float4*)(att + (h1 + x) * 160 + h2) =
                make_float4(acc[x][0], acc[x][1], acc[x][2], acc[x][3]);
    }
    __syncthreads();
    const int wave = tid >> 6, lane = tid & 63;
    for (int rr = 0; rr < 32; rr++) {
        int row = wave * 32 + rr;
        float* ar = att + row * 160;
        float x0 = ar[lane];
        float x1 = ar[lane + 64];
        float x2 = (lane < 32) ? ar[lane + 128] : -3.4e38f;
        float m = fmaxf(fmaxf(x0, x1), x2);
#pragma unroll
        for (int off = 32; off > 0; off >>= 1) m = fmaxf(m, __shfl_xor(m, off));
        float e0 = __expf(x0 - m);
        float e1 = __expf(x1 - m);
        float e2 = (lane < 32) ? __expf(x2 - m) : 0.f;
        float s = e0 + e1 + e2;
#pragma unroll
        for (int off = 32; off > 0; off >>= 1) s += __shfl_xor(s, off);
        float inv = 1.f / s;
        ar[lane] = e0 * inv;
        ar[lane + 64] = e1 * inv;
        if (lane < 32) ar[lane + 128] = e2 * inv;
    }
    float* ts = qs;
    for (int d = 0; d < 3; d++) {
        __syncthreads();
        const float* tg = ws + OFF_T + d * PLANE + b * ICn * HWn + w;
        for (int l = tid; l < 5120; l += 320) {
            int ic = l / 160, hh = l % 160;
            ts[l] = tg[ic * HWn + hh * Ww];
        }
        __syncthreads();
        int h0 = (tid >> 3) * 4;
        int j0 = (tid & 7) * 4;
        float acc[4][4];
#pragma unroll
        for (int x = 0; x < 4; x++)
#pragma unroll
            for (int y = 0; y < 4; y++) acc[x][y] = 0.f;
#pragma unroll 2
        for (int i = 0; i < 160; i++) {
            float4 tv = *(const float4*)(ts + i * 32 + j0);
            float ta[4] = {tv.x, tv.y, tv.z, tv.w};
#pragma unroll
            for (int x = 0; x < 4; x++) {
                float av = att[(h0 + x) * 160 + i];
#pragma unroll
                for (int y = 0; y < 4; y++) acc[x][y] += av * ta[y];
            }
        }
        float* outp = ws + OFF_CAT + (size_t)d * PLANE + (size_t)bw * 5120;
#pragma unroll
        for (int x = 0; x < 4; x++)
            *(float4*)(outp + (h0 + x) * 32 + j0) =
                make_float4(acc[x][0], acc[x][1], acc[x][2], acc[x][3]);
    }
}

// ---------------- output 1x1 conv: GEMM M=256, K=96, N=204800 ----------------
// block 256 = 16 mg (4 ch) x 16 ng (4+4 pos); N-tile 128, M in 4 passes of 64.
__global__ __launch_bounds__(256) void k_out(const float* __restrict__ feat,
                                             const float* __restrict__ ws,
                                             float* __restrict__ out) {
    extern __shared__ float lds[];
    float* As = lds;            // [96][68]  (j-major, pad 68)
    float* Bs = lds + 96 * 68;  // [96][132] (j-major, pad 132)
    const int tid = threadIdx.x;
    const int mg = tid >> 4;
    const int ng = tid & 15;
    const int n0 = blockIdx.x * 128;
    const int b = n0 / HWn;
    const int hw0 = n0 % HWn;
    const float alpha = ws[P_OA];

    // stage Bs: gather CAT (raw-view layout), 12288 floats
#pragma unroll
    for (int i = 0; i < 48; i++) {
        int l = tid + i * 256;
        int j = l % 96, p = l / 96;
        int hw = hw0 + p;
        int h = hw / Ww, w2 = hw % Ww;
        Bs[j * 132 + p] = ws[OFF_CAT + (((size_t)b * Ww + w2) * Hh + h) * 96 + j];
    }
    for (int cb = 0; cb < 4; cb++) {
        __syncthreads();
#pragma unroll
        for (int i = 0; i < 24; i++) {      // As: 96x64 transpose-stage
            int l = tid + i * 256;
            int j = l % 96, c = l / 96;
            As[j * 68 + c] = ws[P_OW + (cb * 64 + c) * 96 + j];
        }
        __syncthreads();
        float acc[4][8];
#pragma unroll
        for (int i = 0; i < 4; i++)
#pragma unroll
            for (int j = 0; j < 8; j++) acc[i][j] = 0.f;
#pragma unroll 4
        for (int j = 0; j < 96; j++) {
            float4 a = *(const float4*)(As + j * 68 + 4 * mg);
            float av[4] = {a.x, a.y, a.z, a.w};
            float4 b0 = *(const float4*)(Bs + j * 132 + 4 * ng);
            float4 b1 = *(const float4*)(Bs + j * 132 + 64 + 4 * ng);
            float bv[8] = {b0.x, b0.y, b0.z, b0.w, b1.x, b1.y, b1.z, b1.w};
#pragma unroll
            for (int i = 0; i < 4; i++)
#pragma unroll
                for (int jj = 0; jj < 8; jj++) acc[i][jj] += av[i] * bv[jj];
        }
#pragma unroll
        for (int i = 0; i < 4; i++) {
            int c = cb * 64 + 4 * mg + i;
            float ob = ws[P_OB + c];
#pragma unroll
            for (int f = 0; f < 2; f++) {
                size_t base = ((size_t)b * Cc + c) * HWn + hw0 + f * 64 + 4 * ng;
                float4 fv = *(const float4*)(feat + base);
                float4 y;
                float t0 = acc[i][f * 4 + 0] + ob + fv.x; y.x = t0 >= 0.f ? t0 : alpha * t0;
                float t1 = acc[i][f * 4 + 1] + ob + fv.y; y.y = t1 >= 0.f ? t1 : alpha * t1;
                float t2 = acc[i][f * 4 + 2] + ob + fv.z; y.z = t2 >= 0.f ? t2 : alpha * t2;
                float t3 = acc[i][f * 4 + 3] + ob + fv.w; y.w = t3 >= 0.f ? t3 : alpha * t3;
                *(float4*)(out + base) = y;
            }
        }
    }
}

extern "C" void kernel_launch(void* const* d_in, const int* in_sizes, int n_in,
                              void* d_out, int out_size, void* d_ws, size_t ws_size,
                              hipStream_t stream) {
    InPtrs ip;
    for (int i = 0; i < 40; i++) ip.p[i] = (const float*)d_in[i];
    float* ws = (float*)d_ws;
    const float* feat = (const float*)d_in[0];
    float* out = (float*)d_out;

    k_prep<<<304, 256, 0, stream>>>(ip, ws);
    k_qkv<<<1600, 256, 0, stream>>>(feat, ws);
    k_dconv<<<dim3(400, 3, 1), 256, 0, stream>>>(ws);
    (void)hipFuncSetAttribute(reinterpret_cast<const void*>(k_att),
                              hipFuncAttributeMaxDynamicSharedMemorySize, 143360);
    k_att<<<1280, 320, 143360, stream>>>(ws);
    (void)hipFuncSetAttribute(reinterpret_cast<const void*>(k_out),
                              hipFuncAttributeMaxDynamicSharedMemorySize, 76800);
    k_out<<<1600, 256, 76800, stream>>>(feat, ws, out);
}

// Round 3
// 812.385 us; speedup vs baseline: 2.3617x; 1.3448x over previous
//
#include <hip/hip_runtime.h>

constexpr int Hh = 160, Ww = 160, Bb = 8, Cc = 256, ICn = 32;
constexpr int HWn = Hh * Ww;                 // 25600
constexpr float EPSf = 1e-5f;

// ws float offsets
constexpr int P_QKVW = 0;        // [256][96]
constexpr int P_QKVB = 24576;    // [96]
constexpr int P_QKVA = 24672;    // [96]
constexpr int P_DW   = 24768;    // [3][32][3][3][32]
constexpr int P_DB   = 52416;    // [3][32]
constexpr int P_OW   = 52512;    // [256][96]
constexpr int P_OB   = 77088;    // [256]
constexpr int P_OA   = 77344;    // [1]
constexpr int PLANE  = Bb * ICn * HWn;       // 6,553,600
constexpr int OFF_Q  = 77824;
constexpr int OFF_K  = OFF_Q + PLANE;
constexpr int OFF_V  = OFF_Q + 2 * PLANE;
constexpr int OFF_T  = OFF_Q + 3 * PLANE;    // t0,t1,t2
constexpr int OFF_CAT= OFF_Q + 6 * PLANE;    // 3*PLANE floats

typedef short bf16x8 __attribute__((ext_vector_type(8)));
typedef float f32x4  __attribute__((ext_vector_type(4)));

__device__ __forceinline__ unsigned f2b(float x) {
    unsigned u = __float_as_uint(x);
    return (u + 0x7FFFu + ((u >> 16) & 1u)) >> 16;   // RNE f32->bf16
}
__device__ __forceinline__ float b2f(unsigned b) { return __uint_as_float(b << 16); }

struct InPtrs { const float* p[40]; };

// ---------------- prep: fold BN into weights/biases ----------------
__global__ void k_prep(InPtrs in, float* __restrict__ ws) {
    int idx = blockIdx.x * 256 + threadIdx.x;
    if (idx < 24576) {
        int c = idx / 96, oc = idx % 96;
        int z = oc >> 5, o = oc & 31;
        const float* wz = in.p[1 + 6 * z];
        float s = in.p[2 + 6 * z][o] * rsqrtf(in.p[5 + 6 * z][o] + EPSf);
        ws[P_QKVW + idx] = wz[o * 256 + c] * s;
    } else if (idx < 24672) {
        int oc = idx - 24576; int z = oc >> 5, o = oc & 31;
        float s = in.p[2 + 6 * z][o] * rsqrtf(in.p[5 + 6 * z][o] + EPSf);
        ws[P_QKVB + oc] = in.p[3 + 6 * z][o] - in.p[4 + 6 * z][o] * s;
    } else if (idx < 24768) {
        int oc = idx - 24672; int z = oc >> 5;
        ws[P_QKVA + oc] = in.p[6 + 6 * z][0];
    } else if (idx < 52416) {
        int j = idx - 24768;
        int d = j / 9216, r2 = j % 9216;
        int oc = r2 & 31; int tmp = r2 >> 5;
        int kx = tmp % 3; tmp /= 3; int ky = tmp % 3; int ic2 = tmp / 3;
        const float* wd = in.p[19 + 5 * d];
        float s = in.p[20 + 5 * d][oc] * rsqrtf(in.p[23 + 5 * d][oc] + EPSf);
        ws[P_DW + j] = wd[((oc * 32 + ic2) * 3 + ky) * 3 + kx] * s;
    } else if (idx < 52512) {
        int j = idx - 52416; int d = j >> 5, oc = j & 31;
        float s = in.p[20 + 5 * d][oc] * rsqrtf(in.p[23 + 5 * d][oc] + EPSf);
        ws[P_DB + j] = in.p[21 + 5 * d][oc] - in.p[22 + 5 * d][oc] * s;
    } else if (idx < 77088) {
        int j = idx - 52512; int c = j / 96;
        float s = in.p[35][c] * rsqrtf(in.p[38][c] + EPSf);
        ws[P_OW + j] = in.p[34][j] * s;
    } else if (idx < 77344) {
        int c = idx - 77088;
        float s = in.p[35][c] * rsqrtf(in.p[38][c] + EPSf);
        ws[P_OB + c] = in.p[36][c] - in.p[37][c] * s;
    } else if (idx == 77344) {
        ws[P_OA] = in.p[39][0];
    }
}

// ---------------- fused q/k/v 1x1 conv: GEMM M=96, K=256, N=204800 ----------------
__global__ __launch_bounds__(256) void k_qkv(const float* __restrict__ feat,
                                             float* __restrict__ ws) {
    __shared__ float As[64 * 96];    // [k][oc]
    __shared__ float Bs[64 * 128];   // [k][pos]
    const int tid = threadIdx.x;
    const int mg = tid >> 4;
    const int ng = tid & 15;
    const int n0 = blockIdx.x * 128;
    const int b = n0 / HWn;
    const int hw0 = n0 % HWn;
    const float* fbase = feat + (size_t)b * Cc * HWn + hw0;
    const float* __restrict__ wq = ws + P_QKVW;
    float acc[6][8];
#pragma unroll
    for (int i = 0; i < 6; i++)
#pragma unroll
        for (int j = 0; j < 8; j++) acc[i][j] = 0.f;

    for (int kc = 0; kc < 4; kc++) {
        __syncthreads();
#pragma unroll
        for (int i = 0; i < 32; i++) {
            int l = tid + i * 256;
            int c = l >> 7, p = l & 127;
            Bs[l] = fbase[(kc * 64 + c) * HWn + p];
        }
#pragma unroll
        for (int i = 0; i < 24; i++) {
            int l = tid + i * 256;
            As[l] = wq[kc * 64 * 96 + l];
        }
        __syncthreads();
#pragma unroll 4
        for (int k = 0; k < 64; k++) {
            float2 a01 = *(const float2*)(As + k * 96 + 6 * mg);
            float2 a23 = *(const float2*)(As + k * 96 + 6 * mg + 2);
            float2 a45 = *(const float2*)(As + k * 96 + 6 * mg + 4);
            float av[6] = {a01.x, a01.y, a23.x, a23.y, a45.x, a45.y};
            float4 b0 = *(const float4*)(Bs + k * 128 + 4 * ng);
            float4 b1 = *(const float4*)(Bs + k * 128 + 64 + 4 * ng);
            float bv[8] = {b0.x, b0.y, b0.z, b0.w, b1.x, b1.y, b1.z, b1.w};
#pragma unroll
            for (int i = 0; i < 6; i++)
#pragma unroll
                for (int j = 0; j < 8; j++) acc[i][j] += av[i] * bv[j];
        }
    }
#pragma unroll
    for (int i = 0; i < 6; i++) {
        int oc = 6 * mg + i;
        float bb = ws[P_QKVB + oc];
        float aa = ws[P_QKVA + oc];
        int z = oc >> 5, o = oc & 31;
        float* qb = ws + OFF_Q + (size_t)z * PLANE + ((size_t)b * ICn + o) * HWn + hw0;
#pragma unroll
        for (int f = 0; f < 2; f++) {
            float4 y;
            float t0 = acc[i][f * 4 + 0] + bb; y.x = t0 >= 0.f ? t0 : aa * t0;
            float t1 = acc[i][f * 4 + 1] + bb; y.y = t1 >= 0.f ? t1 : aa * t1;
            float t2 = acc[i][f * 4 + 2] + bb; y.z = t2 >= 0.f ? t2 : aa * t2;
            float t3 = acc[i][f * 4 + 3] + bb; y.w = t3 >= 0.f ? t3 : aa * t3;
            *(float4*)(qb + f * 64 + 4 * ng) = y;
        }
    }
}

// ---------------- dilated 3x3 convs: weights in LDS, 2 pixels/thread ----------------
__global__ __launch_bounds__(256) void k_dconv(float* __restrict__ ws) {
    __shared__ float wsm[9216];      // [ic][9][32]
    const int d = blockIdx.y;
    const int dil = 1 + 2 * d;
    const int tid = threadIdx.x;
#pragma unroll
    for (int i = 0; i < 36; i++) wsm[tid + i * 256] = ws[P_DW + d * 9216 + tid + i * 256];
    __syncthreads();

    const int pix0 = blockIdx.x * 512 + tid * 2;
    const int b = pix0 / HWn;
    const int hw = pix0 % HWn;
    const int h = hw / Ww, w = hw % Ww;
    const float* __restrict__ vbase = ws + OFF_V + (size_t)b * ICn * HWn;

    int hoff[3]; bool hv[3];
    int wo0[3]; bool wv0[3], wv1[3];
#pragma unroll
    for (int t = 0; t < 3; t++) {
        int hh = h + dil * (t - 1);
        hv[t] = (unsigned)hh < 160u; hoff[t] = hh * Ww;
        int wp = w + dil * (t - 1);
        wv0[t] = (unsigned)wp < 160u; wv1[t] = (unsigned)(wp + 1) < 160u; wo0[t] = wp;
    }

    float acc[32][2];
#pragma unroll
    for (int o = 0; o < 32; o++) { acc[o][0] = 0.f; acc[o][1] = 0.f; }

    for (int ic = 0; ic < ICn; ic++) {
        const float* vp = vbase + ic * HWn;
        float v0[9], v1[9];
#pragma unroll
        for (int ky = 0; ky < 3; ky++)
#pragma unroll
            for (int kx = 0; kx < 3; kx++) {
                int kk = ky * 3 + kx;
                v0[kk] = (hv[ky] && wv0[kx]) ? vp[hoff[ky] + wo0[kx]] : 0.f;
                v1[kk] = (hv[ky] && wv1[kx]) ? vp[hoff[ky] + wo0[kx] + 1] : 0.f;
            }
        const float* wr = wsm + ic * 288;
#pragma unroll
        for (int k = 0; k < 9; k++) {
            float a0 = v0[k], a1 = v1[k];
#pragma unroll
            for (int oq = 0; oq < 8; oq++) {
                float4 wv = *(const float4*)(wr + k * 32 + 4 * oq);
                acc[4 * oq + 0][0] += a0 * wv.x; acc[4 * oq + 0][1] += a1 * wv.x;
                acc[4 * oq + 1][0] += a0 * wv.y; acc[4 * oq + 1][1] += a1 * wv.y;
                acc[4 * oq + 2][0] += a0 * wv.z; acc[4 * oq + 2][1] += a1 * wv.z;
                acc[4 * oq + 3][0] += a0 * wv.w; acc[4 * oq + 3][1] += a1 * wv.w;
            }
        }
    }
    float* tout = ws + OFF_T + (size_t)d * PLANE + (size_t)b * ICn * HWn + hw;
    const float* bd = ws + P_DB + d * 32;
#pragma unroll
    for (int o = 0; o < 32; o++) {
        float2 y;
        y.x = fmaxf(acc[o][0] + bd[o], 0.f);
        y.y = fmaxf(acc[o][1] + bd[o], 0.f);
        *(float2*)(tout + o * HWn) = y;
    }
}

// ---------------- attention: MFMA bf16, frag-linear LDS ----------------
// Stage q/k (hi/lo bf16) as A/B fragments: buf[tile rt][lane][8 bf16] (16B/lane).
__device__ __forceinline__ void stage_qk_hilo(const float* __restrict__ g,
                                              char* hi_buf, char* lo_buf, int tid) {
#pragma unroll
    for (int ss = 0; ss < 2; ss++) {
        int s = tid + ss * 320;          // 640 slots = 10 tiles x 64 lanes
        int l = s & 63, rt = s >> 6;
        int h = 16 * rt + (l & 15);
        int icb = (l >> 4) * 8;
        const float* gp = g + (size_t)icb * HWn + h * Ww;
        unsigned hb[8], lb[8];
#pragma unroll
        for (int v = 0; v < 8; v++) {
            float x = gp[(size_t)v * HWn];
            hb[v] = f2b(x);
            lb[v] = f2b(x - b2f(hb[v]));
        }
        uint4 hv = {hb[0] | (hb[1] << 16), hb[2] | (hb[3] << 16),
                    hb[4] | (hb[5] << 16), hb[6] | (hb[7] << 16)};
        uint4 lv = {lb[0] | (lb[1] << 16), lb[2] | (lb[3] << 16),
                    lb[4] | (lb[5] << 16), lb[6] | (lb[7] << 16)};
        *(uint4*)(hi_buf + s * 16) = hv;
        *(uint4*)(lo_buf + s * 16) = lv;
    }
}

// Stage t as A2 fragments: t_lin[(jt*5+ks)*64 + lane][8 bf16];
// element: jc = 16*jt + (l&15), h2 = 32*ks + 8*(l>>4) + v; faithful raw view:
// flat f = h2*32+jc over the [ic][hh] slice -> ic = f/160, hh = f%160.
__device__ __forceinline__ void stage_t(const float* __restrict__ tg,
                                        char* tbuf, int tid) {
#pragma unroll
    for (int ss = 0; ss < 2; ss++) {
        int s = tid + ss * 320;          // 640 slots
        int l = s & 63;
        int jt = s / 320, ks = (s >> 6) % 5;
        unsigned bb[8];
#pragma unroll
        for (int v = 0; v < 8; v++) {
            int h2 = 32 * ks + 8 * (l >> 4) + v;
            int jc = 16 * jt + (l & 15);
            int f = h2 * 32 + jc;
            int ic = f / 160, hh = f % 160;
            bb[v] = f2b(tg[(size_t)ic * HWn + hh * Ww]);
        }
        uint4 pv = {bb[0] | (bb[1] << 16), bb[2] | (bb[3] << 16),
                    bb[4] | (bb[5] << 16), bb[6] | (bb[7] << 16)};
        *(uint4*)(tbuf + s * 16) = pv;
    }
}

__global__ __launch_bounds__(320) void k_att(float* __restrict__ ws) {
    extern __shared__ char smem[];
    char* q_hi = smem;               // 10240 B each (10 tiles * 64 lanes * 16B)
    char* q_lo = smem + 10240;
    char* k_hi = smem + 20480;
    char* k_lo = smem + 30720;
    char* Sb   = smem;               // 51200 B, reuses q/k region after barrier
    char* tb0  = smem + 51200;       // 10240 B
    char* tb1  = smem + 61440;       // 10240 B
    const int tid = threadIdx.x;
    const int bid = blockIdx.x;
    const int r8 = bid & 7, qq = bid >> 3;   // XCD swizzle
    const int b = qq / 20;
    const int w = r8 * 20 + (qq % 20);
    const int bw = b * Ww + w;
    const int wv = tid >> 6;         // wave 0..4, owns h1 in [32wv, 32wv+32)
    const int l  = tid & 63;
    const int g  = l >> 4;
    const int c  = l & 15;

    const float* qg = ws + OFF_Q + (size_t)b * ICn * HWn + w;
    const float* kg = ws + OFF_K + (size_t)b * ICn * HWn + w;
    stage_qk_hilo(qg, q_hi, q_lo, tid);
    stage_qk_hilo(kg, k_hi, k_lo, tid);
    stage_t(ws + OFF_T + (size_t)b * ICn * HWn + w, tb0, tid);
    __syncthreads();

    // ---- QK^T swapped: S[h2][h1] tiles, D row = h2 = 4g+r (+16rt), col = h1 = c (+16ct+32wv)
    bf16x8 bq[2][2];
#pragma unroll
    for (int ct = 0; ct < 2; ct++) {
        int tau = 2 * wv + ct;
        bq[ct][0] = *(bf16x8*)(q_hi + (tau * 64 + l) * 16);
        bq[ct][1] = *(bf16x8*)(q_lo + (tau * 64 + l) * 16);
    }
    f32x4 acc[10][2];
    f32x4 z4 = {0.f, 0.f, 0.f, 0.f};
#pragma unroll
    for (int rt = 0; rt < 10; rt++) { acc[rt][0] = z4; acc[rt][1] = z4; }
#pragma unroll
    for (int rt = 0; rt < 10; rt++) {
        bf16x8 ah = *(bf16x8*)(k_hi + (rt * 64 + l) * 16);
        bf16x8 al = *(bf16x8*)(k_lo + (rt * 64 + l) * 16);
#pragma unroll
        for (int ct = 0; ct < 2; ct++) {
            acc[rt][ct] = __builtin_amdgcn_mfma_f32_16x16x32_bf16(ah, bq[ct][0], acc[rt][ct], 0, 0, 0);
            acc[rt][ct] = __builtin_amdgcn_mfma_f32_16x16x32_bf16(ah, bq[ct][1], acc[rt][ct], 0, 0, 0);
            acc[rt][ct] = __builtin_amdgcn_mfma_f32_16x16x32_bf16(al, bq[ct][0], acc[rt][ct], 0, 0, 0);
        }
    }
    __syncthreads();   // q/k reads complete everywhere; Sb region now free

    // ---- softmax over h2 (rows): in-register + shfl over lane-groups g
    float mx[2] = {-3.4e38f, -3.4e38f};
#pragma unroll
    for (int rt = 0; rt < 10; rt++)
#pragma unroll
        for (int ct = 0; ct < 2; ct++)
#pragma unroll
            for (int j = 0; j < 4; j++) mx[ct] = fmaxf(mx[ct], acc[rt][ct][j]);
#pragma unroll
    for (int ct = 0; ct < 2; ct++) {
        mx[ct] = fmaxf(mx[ct], __shfl_xor(mx[ct], 16));
        mx[ct] = fmaxf(mx[ct], __shfl_xor(mx[ct], 32));
    }
    float sm[2] = {0.f, 0.f};
#pragma unroll
    for (int rt = 0; rt < 10; rt++)
#pragma unroll
        for (int ct = 0; ct < 2; ct++)
#pragma unroll
            for (int j = 0; j < 4; j++) {
                float e = __expf(acc[rt][ct][j] - mx[ct]);
                acc[rt][ct][j] = e;
                sm[ct] += e;
            }
#pragma unroll
    for (int ct = 0; ct < 2; ct++) {
        sm[ct] += __shfl_xor(sm[ct], 16);
        sm[ct] += __shfl_xor(sm[ct], 32);
    }
    float inv[2] = {1.f / sm[0], 1.f / sm[1]};

    // ---- pack S into PV B-fragment layout: S_lin[((wv*2+ct)*5+ks)*64 + L][16B]
    // lane L = c + 16*(2*(rt&1) + (g>>1)), v-offset 4*(g&1): two bf16 pairs (b64 write)
    const int L = c;  // base; full L computed per rt
#pragma unroll
    for (int rt = 0; rt < 10; rt++) {
#pragma unroll
        for (int ct = 0; ct < 2; ct++) {
            float p0 = acc[rt][ct][0] * inv[ct];
            float p1 = acc[rt][ct][1] * inv[ct];
            float p2 = acc[rt][ct][2] * inv[ct];
            float p3 = acc[rt][ct][3] * inv[ct];
            unsigned d0 = f2b(p0) | (f2b(p1) << 16);
            unsigned d1 = f2b(p2) | (f2b(p3) << 16);
            int Lf = L + 16 * (2 * (rt & 1) + (g >> 1));
            char* dst = Sb + (((wv * 2 + ct) * 5 + (rt >> 1)) * 64 + Lf) * 16 + 8 * (g & 1);
            uint2 dd; dd.x = d0; dd.y = d1;
            *(uint2*)dst = dd;
        }
    }

    // ---- PV per branch: O^T[jc][h1] = sum_h2 t[h2][jc] * S[h2][h1]
    for (int d = 0; d < 3; d++) {
        __syncthreads();   // t(d) staged & visible; prev PV reads of overwrite target done
        if (d < 2)
            stage_t(ws + OFF_T + (size_t)(d + 1) * PLANE + (size_t)b * ICn * HWn + w,
                    (d & 1) ? tb0 : tb1, tid);
        char* tcur = (d & 1) ? tb1 : tb0;
        f32x4 po[2][2];
        po[0][0] = z4; po[0][1] = z4; po[1][0] = z4; po[1][1] = z4;
#pragma unroll
        for (int ks = 0; ks < 5; ks++) {
            bf16x8 a0 = *(bf16x8*)(tcur + ((0 * 5 + ks) * 64 + l) * 16);
            bf16x8 a1 = *(bf16x8*)(tcur + ((1 * 5 + ks) * 64 + l) * 16);
            bf16x8 s0 = *(bf16x8*)(Sb + (((wv * 2 + 0) * 5 + ks) * 64 + l) * 16);
            bf16x8 s1 = *(bf16x8*)(Sb + (((wv * 2 + 1) * 5 + ks) * 64 + l) * 16);
            po[0][0] = __builtin_amdgcn_mfma_f32_16x16x32_bf16(a0, s0, po[0][0], 0, 0, 0);
            po[0][1] = __builtin_amdgcn_mfma_f32_16x16x32_bf16(a0, s1, po[0][1], 0, 0, 0);
            po[1][0] = __builtin_amdgcn_mfma_f32_16x16x32_bf16(a1, s0, po[1][0], 0, 0, 0);
            po[1][1] = __builtin_amdgcn_mfma_f32_16x16x32_bf16(a1, s1, po[1][1], 0, 0, 0);
        }
        float* catp = ws + OFF_CAT + (size_t)d * PLANE + (size_t)bw * 5120;
#pragma unroll
        for (int jt = 0; jt < 2; jt++)
#pragma unroll
            for (int ct = 0; ct < 2; ct++) {
                int h1 = 32 * wv + 16 * ct + c;
                *(f32x4*)(catp + h1 * 32 + 16 * jt + 4 * g) = po[jt][ct];
            }
    }
}

// ---------------- output 1x1 conv: GEMM M=256, K=96, N=204800 ----------------
__global__ __launch_bounds__(256) void k_out(const float* __restrict__ feat,
                                             const float* __restrict__ ws,
                                             float* __restrict__ out) {
    extern __shared__ float lds[];
    float* As = lds;            // [96][68]
    float* Bs = lds + 96 * 68;  // [96][132]
    const int tid = threadIdx.x;
    const int mg = tid >> 4;
    const int ng = tid & 15;
    const int n0 = blockIdx.x * 128;
    const int b = n0 / HWn;
    const int hw0 = n0 % HWn;
    const float alpha = ws[P_OA];

#pragma unroll
    for (int i = 0; i < 48; i++) {
        int l = tid + i * 256;
        int j = l % 96, p = l / 96;
        int hw = hw0 + p;
        int h = hw / Ww, w2 = hw % Ww;
        Bs[j * 132 + p] = ws[OFF_CAT + (((size_t)b * Ww + w2) * Hh + h) * 96 + j];
    }
    for (int cb = 0; cb < 4; cb++) {
        __syncthreads();
#pragma unroll
        for (int i = 0; i < 24; i++) {
            int l = tid + i * 256;
            int j = l % 96, c = l / 96;
            As[j * 68 + c] = ws[P_OW + (cb * 64 + c) * 96 + j];
        }
        __syncthreads();
        float acc[4][8];
#pragma unroll
        for (int i = 0; i < 4; i++)
#pragma unroll
            for (int j = 0; j < 8; j++) acc[i][j] = 0.f;
#pragma unroll 4
        for (int j = 0; j < 96; j++) {
            float4 a = *(const float4*)(As + j * 68 + 4 * mg);
            float av[4] = {a.x, a.y, a.z, a.w};
            float4 b0 = *(const float4*)(Bs + j * 132 + 4 * ng);
            float4 b1 = *(const float4*)(Bs + j * 132 + 64 + 4 * ng);
            float bv[8] = {b0.x, b0.y, b0.z, b0.w, b1.x, b1.y, b1.z, b1.w};
#pragma unroll
            for (int i = 0; i < 4; i++)
#pragma unroll
                for (int jj = 0; jj < 8; jj++) acc[i][jj] += av[i] * bv[jj];
        }
#pragma unroll
        for (int i = 0; i < 4; i++) {
            int c = cb * 64 + 4 * mg + i;
            float ob = ws[P_OB + c];
#pragma unroll
            for (int f = 0; f < 2; f++) {
                size_t base = ((size_t)b * Cc + c) * HWn + hw0 + f * 64 + 4 * ng;
                float4 fv = *(const float4*)(feat + base);
                float4 y;
                float t0 = acc[i][f * 4 + 0] + ob + fv.x; y.x = t0 >= 0.f ? t0 : alpha * t0;
                float t1 = acc[i][f * 4 + 1] + ob + fv.y; y.y = t1 >= 0.f ? t1 : alpha * t1;
                float t2 = acc[i][f * 4 + 2] + ob + fv.z; y.z = t2 >= 0.f ? t2 : alpha * t2;
                float t3 = acc[i][f * 4 + 3] + ob + fv.w; y.w = t3 >= 0.f ? t3 : alpha * t3;
                *(float4*)(out + base) = y;
            }
        }
    }
}

extern "C" void kernel_launch(void* const* d_in, const int* in_sizes, int n_in,
                              void* d_out, int out_size, void* d_ws, size_t ws_size,
                              hipStream_t stream) {
    InPtrs ip;
    for (int i = 0; i < 40; i++) ip.p[i] = (const float*)d_in[i];
    float* ws = (float*)d_ws;
    const float* feat = (const float*)d_in[0];
    float* out = (float*)d_out;

    k_prep<<<304, 256, 0, stream>>>(ip, ws);
    k_qkv<<<1600, 256, 0, stream>>>(feat, ws);
    k_dconv<<<dim3(400, 3, 1), 256, 0, stream>>>(ws);
    (void)hipFuncSetAttribute(reinterpret_cast<const void*>(k_att),
                              hipFuncAttributeMaxDynamicSharedMemorySize, 71680);
    k_att<<<1280, 320, 71680, stream>>>(ws);
    (void)hipFuncSetAttribute(reinterpret_cast<const void*>(k_out),
                              hipFuncAttributeMaxDynamicSharedMemorySize, 76800);
    k_out<<<1600, 256, 76800, stream>>>(feat, ws, out);
}

// Round 4
// 619.186 us; speedup vs baseline: 3.0985x; 1.3120x over previous
//
#include <hip/hip_runtime.h>

constexpr int Hh = 160, Ww = 160, Bb = 8, Cc = 256, ICn = 32;
constexpr int HWn = Hh * Ww;                 // 25600
constexpr float EPSf = 1e-5f;

// ws float offsets
constexpr int P_WQH  = 0;        // ushort[96][256] qkv weight hi
constexpr int P_WQL  = 12288;    // ushort[96][256] qkv weight lo
constexpr int P_QKVB = 24576;    // [96]
constexpr int P_QKVA = 24672;    // [96]
constexpr int P_DW   = 24768;    // [3][32][3][3][32]
constexpr int P_DB   = 52416;    // [3][32]
constexpr int P_OWB  = 52512;    // ushort[256][96] out weight bf16
constexpr int P_OB   = 77088;    // [256]
constexpr int P_OA   = 77344;    // [1]
constexpr int PLANE  = Bb * ICn * HWn;       // 6,553,600
constexpr int OFF_Q  = 77824;
constexpr int OFF_K  = OFF_Q + PLANE;
constexpr int OFF_V  = OFF_Q + 2 * PLANE;
constexpr int OFF_T  = OFF_Q + 3 * PLANE;    // t0,t1,t2 (f32)
constexpr int OFF_CAT= OFF_Q + 6 * PLANE;    // ushort[3*PLANE] (bf16)

typedef unsigned short u16;
typedef short bf16x8 __attribute__((ext_vector_type(8)));
typedef float f32x4  __attribute__((ext_vector_type(4)));

__device__ __forceinline__ unsigned f2b(float x) {
    unsigned u = __float_as_uint(x);
    return (u + 0x7FFFu + ((u >> 16) & 1u)) >> 16;   // RNE f32->bf16
}
__device__ __forceinline__ float b2f(unsigned b) { return __uint_as_float(b << 16); }

struct InPtrs { const float* p[40]; };

// ---------------- prep: fold BN into weights/biases ----------------
__global__ void k_prep(InPtrs in, float* __restrict__ ws) {
    int idx = blockIdx.x * 256 + threadIdx.x;
    if (idx < 24576) {
        int oc = idx >> 8, c = idx & 255;
        int z = oc >> 5, o = oc & 31;
        const float* wz = in.p[1 + 6 * z];
        float s = in.p[2 + 6 * z][o] * rsqrtf(in.p[5 + 6 * z][o] + EPSf);
        float wf = wz[o * 256 + c] * s;
        unsigned hi = f2b(wf);
        unsigned lo = f2b(wf - b2f(hi));
        ((u16*)(ws + P_WQH))[oc * 256 + c] = (u16)hi;
        ((u16*)(ws + P_WQL))[oc * 256 + c] = (u16)lo;
    } else if (idx < 24672) {
        int oc = idx - 24576; int z = oc >> 5, o = oc & 31;
        float s = in.p[2 + 6 * z][o] * rsqrtf(in.p[5 + 6 * z][o] + EPSf);
        ws[P_QKVB + oc] = in.p[3 + 6 * z][o] - in.p[4 + 6 * z][o] * s;
    } else if (idx < 24768) {
        int oc = idx - 24672; int z = oc >> 5;
        ws[P_QKVA + oc] = in.p[6 + 6 * z][0];
    } else if (idx < 52416) {
        int j = idx - 24768;
        int d = j / 9216, r2 = j % 9216;
        int oc = r2 & 31; int tmp = r2 >> 5;
        int kx = tmp % 3; tmp /= 3; int ky = tmp % 3; int ic2 = tmp / 3;
        const float* wd = in.p[19 + 5 * d];
        float s = in.p[20 + 5 * d][oc] * rsqrtf(in.p[23 + 5 * d][oc] + EPSf);
        ws[P_DW + j] = wd[((oc * 32 + ic2) * 3 + ky) * 3 + kx] * s;
    } else if (idx < 52512) {
        int j = idx - 52416; int d = j >> 5, oc = j & 31;
        float s = in.p[20 + 5 * d][oc] * rsqrtf(in.p[23 + 5 * d][oc] + EPSf);
        ws[P_DB + j] = in.p[21 + 5 * d][oc] - in.p[22 + 5 * d][oc] * s;
    } else if (idx < 77088) {
        int j2 = idx - 52512; int c = j2 / 96;
        float s = in.p[35][c] * rsqrtf(in.p[38][c] + EPSf);
        ((u16*)(ws + P_OWB))[j2] = (u16)f2b(in.p[34][j2] * s);
    } else if (idx < 77344) {
        int c = idx - 77088;
        float s = in.p[35][c] * rsqrtf(in.p[38][c] + EPSf);
        ws[P_OB + c] = in.p[36][c] - in.p[37][c] * s;
    } else if (idx == 77344) {
        ws[P_OA] = in.p[39][0];
    }
}

// ---------------- q/k/v 1x1 conv: bf16 hi/lo MFMA GEMM M=96,K=256,N=204800 ----------------
// block 256 = 4 waves; N-tile 128 (wave -> 2 n-tiles); K chunked by 64.
__global__ __launch_bounds__(256) void k_qkv(const float* __restrict__ feat,
                                             float* __restrict__ ws) {
    __shared__ u16 BhS[8192];   // 16 slots(ks,nt) x 64 lanes x 8 bf16
    __shared__ u16 BlS[8192];
    const int tid = threadIdx.x;
    const int wv = tid >> 6, l = tid & 63;
    const int g = l >> 4, c15 = l & 15;
    const int n0 = blockIdx.x * 128;
    const int b = n0 / HWn, hw0 = n0 % HWn;
    const float* fbase = feat + (size_t)b * Cc * HWn + hw0;
    const u16* __restrict__ WQH = (const u16*)(ws + P_WQH);
    const u16* __restrict__ WQL = (const u16*)(ws + P_WQL);
    f32x4 acc[6][2];
    f32x4 z4 = {0.f, 0.f, 0.f, 0.f};
#pragma unroll
    for (int mt = 0; mt < 6; mt++) { acc[mt][0] = z4; acc[mt][1] = z4; }

    for (int kc = 0; kc < 4; kc++) {
        __syncthreads();
#pragma unroll
        for (int ss = 0; ss < 4; ss++) {      // 1024 slots
            int s = tid + ss * 256;
            int sl = s & 63, si = s >> 6;     // si = ks*8+nt
            int k0 = kc * 64 + (si >> 3) * 32 + (sl >> 4) * 8;
            int nn = (si & 7) * 16 + (sl & 15);
            const float* gp = fbase + (size_t)k0 * HWn + nn;
            unsigned hb[8], lb[8];
#pragma unroll
            for (int v = 0; v < 8; v++) {
                float x = gp[(size_t)v * HWn];
                hb[v] = f2b(x);
                lb[v] = f2b(x - b2f(hb[v]));
            }
            uint4 hv = {hb[0] | (hb[1] << 16), hb[2] | (hb[3] << 16),
                        hb[4] | (hb[5] << 16), hb[6] | (hb[7] << 16)};
            uint4 lv = {lb[0] | (lb[1] << 16), lb[2] | (lb[3] << 16),
                        lb[4] | (lb[5] << 16), lb[6] | (lb[7] << 16)};
            *(uint4*)(&BhS[(si * 64 + sl) * 8]) = hv;
            *(uint4*)(&BlS[(si * 64 + sl) * 8]) = lv;
        }
        __syncthreads();
#pragma unroll
        for (int ks = 0; ks < 2; ks++) {
            bf16x8 bh[2], bl[2];
#pragma unroll
            for (int ntl = 0; ntl < 2; ntl++) {
                int nt = wv * 2 + ntl;
                bh[ntl] = *(const bf16x8*)(&BhS[((ks * 8 + nt) * 64 + l) * 8]);
                bl[ntl] = *(const bf16x8*)(&BlS[((ks * 8 + nt) * 64 + l) * 8]);
            }
#pragma unroll
            for (int mt = 0; mt < 6; mt++) {
                int arow = (16 * mt + c15) * 256 + kc * 64 + ks * 32 + g * 8;
                bf16x8 ah = *(const bf16x8*)(WQH + arow);
                bf16x8 al = *(const bf16x8*)(WQL + arow);
#pragma unroll
                for (int ntl = 0; ntl < 2; ntl++) {
                    acc[mt][ntl] = __builtin_amdgcn_mfma_f32_16x16x32_bf16(ah, bh[ntl], acc[mt][ntl], 0, 0, 0);
                    acc[mt][ntl] = __builtin_amdgcn_mfma_f32_16x16x32_bf16(ah, bl[ntl], acc[mt][ntl], 0, 0, 0);
                    acc[mt][ntl] = __builtin_amdgcn_mfma_f32_16x16x32_bf16(al, bh[ntl], acc[mt][ntl], 0, 0, 0);
                }
            }
        }
    }
    // epilogue: bias + PReLU, scatter to f32 q/k/v planes
#pragma unroll
    for (int mt = 0; mt < 6; mt++)
#pragma unroll
        for (int ntl = 0; ntl < 2; ntl++) {
            int pos = hw0 + (wv * 2 + ntl) * 16 + c15;
#pragma unroll
            for (int jr = 0; jr < 4; jr++) {
                int oc = 16 * mt + 4 * g + jr;
                float bb = ws[P_QKVB + oc];
                float aa = ws[P_QKVA + oc];
                float y = acc[mt][ntl][jr] + bb;
                y = y >= 0.f ? y : aa * y;
                int z = oc >> 5, o = oc & 31;
                ws[OFF_Q + (size_t)z * PLANE + ((size_t)b * ICn + o) * HWn + pos] = y;
            }
        }
}

// ---------------- dilated 3x3 convs: weights in LDS, 2 pixels/thread ----------------
__global__ __launch_bounds__(256) void k_dconv(float* __restrict__ ws) {
    __shared__ float wsm[9216];      // [ic][9][32]
    const int d = blockIdx.y;
    const int dil = 1 + 2 * d;
    const int tid = threadIdx.x;
#pragma unroll
    for (int i = 0; i < 36; i++) wsm[tid + i * 256] = ws[P_DW + d * 9216 + tid + i * 256];
    __syncthreads();

    const int pix0 = blockIdx.x * 512 + tid * 2;
    const int b = pix0 / HWn;
    const int hw = pix0 % HWn;
    const int h = hw / Ww, w = hw % Ww;
    const float* __restrict__ vbase = ws + OFF_V + (size_t)b * ICn * HWn;

    int hoff[3]; bool hv[3];
    int wo0[3]; bool wv0[3], wv1[3];
#pragma unroll
    for (int t = 0; t < 3; t++) {
        int hh = h + dil * (t - 1);
        hv[t] = (unsigned)hh < 160u; hoff[t] = hh * Ww;
        int wp = w + dil * (t - 1);
        wv0[t] = (unsigned)wp < 160u; wv1[t] = (unsigned)(wp + 1) < 160u; wo0[t] = wp;
    }

    float acc[32][2];
#pragma unroll
    for (int o = 0; o < 32; o++) { acc[o][0] = 0.f; acc[o][1] = 0.f; }

    for (int ic = 0; ic < ICn; ic++) {
        const float* vp = vbase + ic * HWn;
        float v0[9], v1[9];
#pragma unroll
        for (int ky = 0; ky < 3; ky++)
#pragma unroll
            for (int kx = 0; kx < 3; kx++) {
                int kk = ky * 3 + kx;
                v0[kk] = (hv[ky] && wv0[kx]) ? vp[hoff[ky] + wo0[kx]] : 0.f;
                v1[kk] = (hv[ky] && wv1[kx]) ? vp[hoff[ky] + wo0[kx] + 1] : 0.f;
            }
        const float* wr = wsm + ic * 288;
#pragma unroll
        for (int k = 0; k < 9; k++) {
            float a0 = v0[k], a1 = v1[k];
#pragma unroll
            for (int oq = 0; oq < 8; oq++) {
                float4 wv = *(const float4*)(wr + k * 32 + 4 * oq);
                acc[4 * oq + 0][0] += a0 * wv.x; acc[4 * oq + 0][1] += a1 * wv.x;
                acc[4 * oq + 1][0] += a0 * wv.y; acc[4 * oq + 1][1] += a1 * wv.y;
                acc[4 * oq + 2][0] += a0 * wv.z; acc[4 * oq + 2][1] += a1 * wv.z;
                acc[4 * oq + 3][0] += a0 * wv.w; acc[4 * oq + 3][1] += a1 * wv.w;
            }
        }
    }
    float* tout = ws + OFF_T + (size_t)d * PLANE + (size_t)b * ICn * HWn + hw;
    const float* bd = ws + P_DB + d * 32;
#pragma unroll
    for (int o = 0; o < 32; o++) {
        float2 y;
        y.x = fmaxf(acc[o][0] + bd[o], 0.f);
        y.y = fmaxf(acc[o][1] + bd[o], 0.f);
        *(float2*)(tout + o * HWn) = y;
    }
}

// ---------------- attention: MFMA bf16, frag-linear LDS ----------------
__device__ __forceinline__ void stage_qk_hilo(const float* __restrict__ g,
                                              char* hi_buf, char* lo_buf, int tid) {
#pragma unroll
    for (int ss = 0; ss < 2; ss++) {
        int s = tid + ss * 320;          // 640 slots = 10 tiles x 64 lanes
        int l = s & 63, rt = s >> 6;
        int h = 16 * rt + (l & 15);
        int icb = (l >> 4) * 8;
        const float* gp = g + (size_t)icb * HWn + h * Ww;
        unsigned hb[8], lb[8];
#pragma unroll
        for (int v = 0; v < 8; v++) {
            float x = gp[(size_t)v * HWn];
            hb[v] = f2b(x);
            lb[v] = f2b(x - b2f(hb[v]));
        }
        uint4 hv = {hb[0] | (hb[1] << 16), hb[2] | (hb[3] << 16),
                    hb[4] | (hb[5] << 16), hb[6] | (hb[7] << 16)};
        uint4 lv = {lb[0] | (lb[1] << 16), lb[2] | (lb[3] << 16),
                    lb[4] | (lb[5] << 16), lb[6] | (lb[7] << 16)};
        *(uint4*)(hi_buf + s * 16) = hv;
        *(uint4*)(lo_buf + s * 16) = lv;
    }
}

__device__ __forceinline__ void stage_t(const float* __restrict__ tg,
                                        char* tbuf, int tid) {
#pragma unroll
    for (int ss = 0; ss < 2; ss++) {
        int s = tid + ss * 320;          // 640 slots
        int l = s & 63;
        int jt = s / 320, ks = (s >> 6) % 5;
        unsigned bb[8];
#pragma unroll
        for (int v = 0; v < 8; v++) {
            int h2 = 32 * ks + 8 * (l >> 4) + v;
            int jc = 16 * jt + (l & 15);
            int f = h2 * 32 + jc;
            int ic = f / 160, hh = f % 160;
            bb[v] = f2b(tg[(size_t)ic * HWn + hh * Ww]);
        }
        uint4 pv = {bb[0] | (bb[1] << 16), bb[2] | (bb[3] << 16),
                    bb[4] | (bb[5] << 16), bb[6] | (bb[7] << 16)};
        *(uint4*)(tbuf + s * 16) = pv;
    }
}

__global__ __launch_bounds__(320) void k_att(float* __restrict__ ws) {
    extern __shared__ char smem[];
    char* q_hi = smem;               // 10240 B each
    char* q_lo = smem + 10240;
    char* k_hi = smem + 20480;
    char* k_lo = smem + 30720;
    char* Sb   = smem;               // 51200 B, reuses q/k region after barrier
    char* tb0  = smem + 51200;       // 10240 B
    char* tb1  = smem + 61440;       // 10240 B
    const int tid = threadIdx.x;
    const int bid = blockIdx.x;
    const int r8 = bid & 7, qq = bid >> 3;   // XCD swizzle
    const int b = qq / 20;
    const int w = r8 * 20 + (qq % 20);
    const int bw = b * Ww + w;
    const int wv = tid >> 6;
    const int l  = tid & 63;
    const int g  = l >> 4;
    const int c  = l & 15;

    const float* qg = ws + OFF_Q + (size_t)b * ICn * HWn + w;
    const float* kg = ws + OFF_K + (size_t)b * ICn * HWn + w;
    stage_qk_hilo(qg, q_hi, q_lo, tid);
    stage_qk_hilo(kg, k_hi, k_lo, tid);
    stage_t(ws + OFF_T + (size_t)b * ICn * HWn + w, tb0, tid);
    __syncthreads();

    bf16x8 bq[2][2];
#pragma unroll
    for (int ct = 0; ct < 2; ct++) {
        int tau = 2 * wv + ct;
        bq[ct][0] = *(bf16x8*)(q_hi + (tau * 64 + l) * 16);
        bq[ct][1] = *(bf16x8*)(q_lo + (tau * 64 + l) * 16);
    }
    f32x4 acc[10][2];
    f32x4 z4 = {0.f, 0.f, 0.f, 0.f};
#pragma unroll
    for (int rt = 0; rt < 10; rt++) { acc[rt][0] = z4; acc[rt][1] = z4; }
#pragma unroll
    for (int rt = 0; rt < 10; rt++) {
        bf16x8 ah = *(bf16x8*)(k_hi + (rt * 64 + l) * 16);
        bf16x8 al = *(bf16x8*)(k_lo + (rt * 64 + l) * 16);
#pragma unroll
        for (int ct = 0; ct < 2; ct++) {
            acc[rt][ct] = __builtin_amdgcn_mfma_f32_16x16x32_bf16(ah, bq[ct][0], acc[rt][ct], 0, 0, 0);
            acc[rt][ct] = __builtin_amdgcn_mfma_f32_16x16x32_bf16(ah, bq[ct][1], acc[rt][ct], 0, 0, 0);
            acc[rt][ct] = __builtin_amdgcn_mfma_f32_16x16x32_bf16(al, bq[ct][0], acc[rt][ct], 0, 0, 0);
        }
    }
    __syncthreads();

    float mx[2] = {-3.4e38f, -3.4e38f};
#pragma unroll
    for (int rt = 0; rt < 10; rt++)
#pragma unroll
        for (int ct = 0; ct < 2; ct++)
#pragma unroll
            for (int j = 0; j < 4; j++) mx[ct] = fmaxf(mx[ct], acc[rt][ct][j]);
#pragma unroll
    for (int ct = 0; ct < 2; ct++) {
        mx[ct] = fmaxf(mx[ct], __shfl_xor(mx[ct], 16));
        mx[ct] = fmaxf(mx[ct], __shfl_xor(mx[ct], 32));
    }
    float sm[2] = {0.f, 0.f};
#pragma unroll
    for (int rt = 0; rt < 10; rt++)
#pragma unroll
        for (int ct = 0; ct < 2; ct++)
#pragma unroll
            for (int j = 0; j < 4; j++) {
                float e = __expf(acc[rt][ct][j] - mx[ct]);
                acc[rt][ct][j] = e;
                sm[ct] += e;
            }
#pragma unroll
    for (int ct = 0; ct < 2; ct++) {
        sm[ct] += __shfl_xor(sm[ct], 16);
        sm[ct] += __shfl_xor(sm[ct], 32);
    }
    float inv[2] = {1.f / sm[0], 1.f / sm[1]};

#pragma unroll
    for (int rt = 0; rt < 10; rt++) {
#pragma unroll
        for (int ct = 0; ct < 2; ct++) {
            float p0 = acc[rt][ct][0] * inv[ct];
            float p1 = acc[rt][ct][1] * inv[ct];
            float p2 = acc[rt][ct][2] * inv[ct];
            float p3 = acc[rt][ct][3] * inv[ct];
            unsigned d0 = f2b(p0) | (f2b(p1) << 16);
            unsigned d1 = f2b(p2) | (f2b(p3) << 16);
            int Lf = c + 16 * (2 * (rt & 1) + (g >> 1));
            char* dst = Sb + (((wv * 2 + ct) * 5 + (rt >> 1)) * 64 + Lf) * 16 + 8 * (g & 1);
            uint2 dd; dd.x = d0; dd.y = d1;
            *(uint2*)dst = dd;
        }
    }

    u16* catb = (u16*)(ws + OFF_CAT);
    for (int d = 0; d < 3; d++) {
        __syncthreads();
        if (d < 2)
            stage_t(ws + OFF_T + (size_t)(d + 1) * PLANE + (size_t)b * ICn * HWn + w,
                    (d & 1) ? tb0 : tb1, tid);
        char* tcur = (d & 1) ? tb1 : tb0;
        f32x4 po[2][2];
        po[0][0] = z4; po[0][1] = z4; po[1][0] = z4; po[1][1] = z4;
#pragma unroll
        for (int ks = 0; ks < 5; ks++) {
            bf16x8 a0 = *(bf16x8*)(tcur + ((0 * 5 + ks) * 64 + l) * 16);
            bf16x8 a1 = *(bf16x8*)(tcur + ((1 * 5 + ks) * 64 + l) * 16);
            bf16x8 s0 = *(bf16x8*)(Sb + (((wv * 2 + 0) * 5 + ks) * 64 + l) * 16);
            bf16x8 s1 = *(bf16x8*)(Sb + (((wv * 2 + 1) * 5 + ks) * 64 + l) * 16);
            po[0][0] = __builtin_amdgcn_mfma_f32_16x16x32_bf16(a0, s0, po[0][0], 0, 0, 0);
            po[0][1] = __builtin_amdgcn_mfma_f32_16x16x32_bf16(a0, s1, po[0][1], 0, 0, 0);
            po[1][0] = __builtin_amdgcn_mfma_f32_16x16x32_bf16(a1, s0, po[1][0], 0, 0, 0);
            po[1][1] = __builtin_amdgcn_mfma_f32_16x16x32_bf16(a1, s1, po[1][1], 0, 0, 0);
        }
#pragma unroll
        for (int jt = 0; jt < 2; jt++)
#pragma unroll
            for (int ct = 0; ct < 2; ct++) {
                int h1 = 32 * wv + 16 * ct + c;
                size_t idx = (size_t)d * PLANE + (size_t)bw * 5120 + h1 * 32 + 16 * jt + 4 * g;
                f32x4 v = po[jt][ct];
                uint2 dd;
                dd.x = f2b(v[0]) | (f2b(v[1]) << 16);
                dd.y = f2b(v[2]) | (f2b(v[3]) << 16);
                *(uint2*)(catb + idx) = dd;
            }
    }
}

// ---------------- output 1x1 conv: bf16 MFMA GEMM M=256,K=96,N=204800 ----------------
// block 256 = 4 waves; wave owns 64 channels; N-tile 128 in 2 passes of 64.
__global__ __launch_bounds__(256) void k_out(const float* __restrict__ feat,
                                             const float* __restrict__ ws,
                                             float* __restrict__ out) {
    __shared__ u16 Bs[12288];   // 24 slots(ks,nt) x 64 lanes x 8 bf16
    const int tid = threadIdx.x;
    const int wv = tid >> 6, l = tid & 63;
    const int g = l >> 4, c15 = l & 15;
    const int n0 = blockIdx.x * 128;
    const int b = n0 / HWn, hw0 = n0 % HWn;
    const u16* __restrict__ CATb = (const u16*)(ws + OFF_CAT);
    const u16* __restrict__ OWB = (const u16*)(ws + P_OWB);

    // stage B fragments: p from (nt,c15), j from (ks,g) -> 8 consecutive j = 16B load
#pragma unroll
    for (int ss = 0; ss < 6; ss++) {
        int s = tid + ss * 256;
        int sl = s & 63, si = s >> 6;    // si = ks*8+nt, 0..23
        int p = (si & 7) * 16 + (sl & 15);
        int hw = hw0 + p;
        int h = hw / Ww, w2 = hw % Ww;
        int j = (si >> 3) * 32 + (sl >> 4) * 8;
        size_t flat = ((size_t)(b * Ww + w2) * Hh + h) * 96 + j;
        *(uint4*)(&Bs[(si * 64 + sl) * 8]) = *(const uint4*)(CATb + flat);
    }
    // preload A fragments (L2-resident weights)
    bf16x8 af[4][3];
#pragma unroll
    for (int mt = 0; mt < 4; mt++)
#pragma unroll
        for (int ks = 0; ks < 3; ks++)
            af[mt][ks] = *(const bf16x8*)(OWB + (wv * 64 + mt * 16 + c15) * 96 + ks * 32 + g * 8);
    __syncthreads();
    const float alpha = ws[P_OA];

    f32x4 z4 = {0.f, 0.f, 0.f, 0.f};
#pragma unroll
    for (int np = 0; np < 2; np++) {
        f32x4 acc[4][4];
#pragma unroll
        for (int mt = 0; mt < 4; mt++)
#pragma unroll
            for (int ntl = 0; ntl < 4; ntl++) acc[mt][ntl] = z4;
#pragma unroll
        for (int ks = 0; ks < 3; ks++) {
            bf16x8 bf_[4];
#pragma unroll
            for (int ntl = 0; ntl < 4; ntl++)
                bf_[ntl] = *(const bf16x8*)(&Bs[((ks * 8 + np * 4 + ntl) * 64 + l) * 8]);
#pragma unroll
            for (int mt = 0; mt < 4; mt++)
#pragma unroll
                for (int ntl = 0; ntl < 4; ntl++)
                    acc[mt][ntl] = __builtin_amdgcn_mfma_f32_16x16x32_bf16(af[mt][ks], bf_[ntl], acc[mt][ntl], 0, 0, 0);
        }
        // epilogue: bias + residual + PReLU
#pragma unroll
        for (int mt = 0; mt < 4; mt++)
#pragma unroll
            for (int ntl = 0; ntl < 4; ntl++) {
                int p = (np * 4 + ntl) * 16 + c15;
#pragma unroll
                for (int jr = 0; jr < 4; jr++) {
                    int cch = wv * 64 + mt * 16 + 4 * g + jr;
                    size_t base = ((size_t)b * Cc + cch) * HWn + hw0 + p;
                    float y = acc[mt][ntl][jr] + ws[P_OB + cch] + feat[base];
                    out[base] = y >= 0.f ? y : alpha * y;
                }
            }
    }
}

extern "C" void kernel_launch(void* const* d_in, const int* in_sizes, int n_in,
                              void* d_out, int out_size, void* d_ws, size_t ws_size,
                              hipStream_t stream) {
    InPtrs ip;
    for (int i = 0; i < 40; i++) ip.p[i] = (const float*)d_in[i];
    float* ws = (float*)d_ws;
    const float* feat = (const float*)d_in[0];
    float* out = (float*)d_out;

    k_prep<<<304, 256, 0, stream>>>(ip, ws);
    k_qkv<<<1600, 256, 0, stream>>>(feat, ws);
    k_dconv<<<dim3(400, 3, 1), 256, 0, stream>>>(ws);
    (void)hipFuncSetAttribute(reinterpret_cast<const void*>(k_att),
                              hipFuncAttributeMaxDynamicSharedMemorySize, 71680);
    k_att<<<1280, 320, 71680, stream>>>(ws);
    k_out<<<1600, 256, 0, stream>>>(feat, ws, out);
}